// Round 11
// baseline (42.613 us; speedup 1.0000x reference)
//
#include <hip/hip_runtime.h>
#include <hip/hip_fp16.h>

// out[m][n] = fp16( fp16( (sum_k x[m][k]*w6[n][k]) * scale[n] ) + bias[n] ), stored fp32
// Inputs pushed as fp32 (fp16-exact) -> fp32 LDS via global_load_lds DMA (no VGPR
// roundtrip -> compiler cannot serialize staging; rounds 3/6/8/9 all died there),
// cvt fp16 in the fragment path (exact), f16 MFMA, fp32 acc.
// XOR chunk swizzle (rule #21: inverse-swizzled global source + swizzled ds_read)
// kills the 16-way bank conflict that linear rows would have.

typedef __attribute__((ext_vector_type(8))) _Float16 half8;
typedef __attribute__((ext_vector_type(2))) __fp16 fp16x2;   // cvt_pkrtz return type
typedef __attribute__((ext_vector_type(4))) float f32x4;

typedef const __attribute__((address_space(1))) void* gptr_t;
typedef __attribute__((address_space(3))) void* lptr_t;

constexpr int K  = 4096;
constexpr int N  = 4096;
constexpr int M  = 256;
constexpr int BM = 128;
constexpr int BN = 128;
constexpr int BK = 32;
constexpr int SPL  = 4;
constexpr int KSPL = K / SPL;       // 1024
constexpr int NT   = KSPL / BK;     // 32 phases
constexpr int TILEF = BM * BK;      // 4096 floats = 16 KB per op-tile
// lds: float[buf2][op2][128 rows][32 floats]  = 65,536 B total (2 ops x 2 bufs)

__device__ __forceinline__ void gload16(const float* g, float* l) {
    __builtin_amdgcn_global_load_lds((gptr_t)g, (lptr_t)l, 16, 0, 0);
}

__device__ __forceinline__ half8 cvt8(float4 f0, float4 f1) {   // exact: fp16-exact data
    fp16x2 p0 = __builtin_amdgcn_cvt_pkrtz(f0.x, f0.y);
    fp16x2 p1 = __builtin_amdgcn_cvt_pkrtz(f0.z, f0.w);
    fp16x2 p2 = __builtin_amdgcn_cvt_pkrtz(f1.x, f1.y);
    fp16x2 p3 = __builtin_amdgcn_cvt_pkrtz(f1.z, f1.w);
    half8 h;
    h[0]=(_Float16)p0[0]; h[1]=(_Float16)p0[1];
    h[2]=(_Float16)p1[0]; h[3]=(_Float16)p1[1];
    h[4]=(_Float16)p2[0]; h[5]=(_Float16)p2[1];
    h[6]=(_Float16)p3[0]; h[7]=(_Float16)p3[1];
    return h;
}

__global__ __launch_bounds__(512, 2)
void fp6lin_gemm(const float* __restrict__ X,
                 const float* __restrict__ W,
                 float* __restrict__ P)      // [SPL][M][N] fp32 partials
{
    __shared__ __align__(16) float lds[2 * 2 * TILEF];   // 64 KB

    const int tid = (int)threadIdx.x;
    const int w8  = tid >> 6;           // wave 0..7
    const int l   = tid & 63;
    const int lc  = l & 15;             // frag row-in-16
    const int lr  = l >> 4;             // frag k-group

    // XCD swizzle: grid 256 = 8 XCDs x 32; bm fastest within XCD -> the 2 blocks
    // sharing a W k-panel are co-resident (W HBM-read once).
    const int bid   = (int)blockIdx.x;
    const int xcd   = bid & 7;
    const int idx   = bid >> 3;              // 0..31
    const int bm    = (idx & 1) * BM;        // 2 M-tiles
    const int combo = xcd * 16 + (idx >> 1); // 0..127
    const int sp    = combo & 3;             // 4 K-splits
    const int bn    = (combo >> 2) * BN;     // 32 N-tiles
    const int kb    = sp * KSPL;

    // ---- staging (DMA) map -------------------------------------------------
    // 32 KB/phase = 32 segs of 1 KB (8 rows x 128 B). wave w8 owns segs {2w8, 2w8+1}
    // per op. lane l -> row-in-seg l>>3, chunk-in-row l&7. LDS is linear
    // (base + lane*16); global source pre-swizzled: data chunk c = (l&7) ^ (row&7).
    const int l8 = l >> 3;               // 0..7 row within segment
    const int c8 = (l & 7) ^ l8;         // inverse-swizzled source chunk (row&7 == l8)
    const int r0 = 16 * w8 + l8;         // issue i adds 8*i
    const float* xg0 = X + (size_t)(bm + r0)     * K + kb + 4 * c8;
    const float* xg1 = X + (size_t)(bm + r0 + 8) * K + kb + 4 * c8;
    const float* wg0 = W + (size_t)(bn + r0)     * K + kb + 4 * c8;
    const float* wg1 = W + (size_t)(bn + r0 + 8) * K + kb + 4 * c8;
    const int sx0 = (w8 * 2 + 0) * 256;  // LDS float-offset of segment (wave-uniform)
    const int sx1 = (w8 * 2 + 1) * 256;

#define STAGE(t, bf) do { float* Lb = lds + (bf) * 2 * TILEF;            \
        gload16(xg0 + (t) * BK, Lb + sx0);                               \
        gload16(xg1 + (t) * BK, Lb + sx1);                               \
        gload16(wg0 + (t) * BK, Lb + TILEF + sx0);                       \
        gload16(wg1 + (t) * BK, Lb + TILEF + sx1); } while (0)

    // ---- compute map -------------------------------------------------------
    const int wm = (w8 & 1) * 64;        // wave tile 64 x 32
    const int wn = (w8 >> 1) * 32;
    // frag rows are wm/wn + 16*q + lc -> row&7 == lc&7 for all frags.
    // k chunks: c0 = 2*lr + {0,1}; swizzled offsets (floats):
    const int o0 = (((lr * 2)     ^ (lc & 7)) << 2);
    const int o1 = (((lr * 2 + 1) ^ (lc & 7)) << 2);

    f32x4 acc[4][2];
    #pragma unroll
    for (int a = 0; a < 4; ++a)
        #pragma unroll
        for (int b = 0; b < 2; ++b)
            acc[a][b] = (f32x4){0.f, 0.f, 0.f, 0.f};

#define COMPUTE(bf) do {                                                 \
        const float* LA = lds + (bf) * 2 * TILEF;                        \
        const float* LB = LA + TILEF;                                    \
        half8 af[4], bb[2];                                              \
        _Pragma("unroll")                                                \
        for (int ar = 0; ar < 4; ++ar) {                                 \
            const float* p = LA + (wm + ar * 16 + lc) * BK;              \
            af[ar] = cvt8(*(const float4*)(p + o0), *(const float4*)(p + o1)); \
        }                                                                \
        _Pragma("unroll")                                                \
        for (int br = 0; br < 2; ++br) {                                 \
            const float* p = LB + (wn + br * 16 + lc) * BK;              \
            bb[br] = cvt8(*(const float4*)(p + o0), *(const float4*)(p + o1)); \
        }                                                                \
        _Pragma("unroll")                                                \
        for (int ar = 0; ar < 4; ++ar)                                   \
            _Pragma("unroll")                                            \
            for (int br = 0; br < 2; ++br)                               \
                acc[ar][br] = __builtin_amdgcn_mfma_f32_16x16x32_f16(    \
                    af[ar], bb[br], acc[ar][br], 0, 0, 0); } while (0)

    // prologue: tile 0 -> buf 0 (barrier drains DMA: hipcc emits vmcnt(0) there)
    STAGE(0, 0);
    __syncthreads();

    for (int t = 0; t < NT; ++t) {
        const int cur = t & 1;
        if (t + 1 < NT) STAGE(t + 1, cur ^ 1);   // async DMA, runs under COMPUTE
        COMPUTE(cur);
        __syncthreads();                         // drain + buffer handoff
    }
#undef STAGE
#undef COMPUTE

    // streamed partial stores. C/D: col=lane&15, row=(lane>>4)*4+reg [m89/m91]
    float* Pb = P + (size_t)sp * M * N;
    const int orow = bm + wm + lr * 4;
    const int ocol = bn + wn + lc;
    #pragma unroll
    for (int ar = 0; ar < 4; ++ar)
        #pragma unroll
        for (int br = 0; br < 2; ++br)
            #pragma unroll
            for (int r = 0; r < 4; ++r)
                Pb[(size_t)(orow + ar * 16 + r) * N + ocol + br * 16] = acc[ar][br][r];
}

// O = fp32( fp16( fp16( (sum of SPL partials) * scale[n] ) + bias[n] ) )
template <int SPLT>
__global__ __launch_bounds__(256)
void fp6lin_finalize(const float* __restrict__ P,
                     const float* __restrict__ S,
                     const float* __restrict__ Bi,
                     float* __restrict__ O)
{
    const size_t i = ((size_t)blockIdx.x * 256 + threadIdx.x) * 4;
    const int n = (int)(i & (N - 1));
    float4 v = *(const float4*)(P + i);
    #pragma unroll
    for (int s = 1; s < SPLT; ++s) {
        float4 u = *(const float4*)(P + (size_t)s * M * N + i);
        v.x += u.x; v.y += u.y; v.z += u.z; v.w += u.w;
    }
    float4 sc = *(const float4*)(S + n);
    float4 bb = *(const float4*)(Bi + n);
    v.x = (float)(_Float16)((float)(_Float16)(v.x * sc.x) + bb.x);
    v.y = (float)(_Float16)((float)(_Float16)(v.y * sc.y) + bb.y);
    v.z = (float)(_Float16)((float)(_Float16)(v.z * sc.z) + bb.z);
    v.w = (float)(_Float16)((float)(_Float16)(v.w * sc.w) + bb.w);
    *(float4*)(O + i) = v;
}

// correctness fallback if d_ws is too small for SPL partial slices
__global__ __launch_bounds__(256)
void fp6lin_small(const float* __restrict__ X, const float* __restrict__ W,
                  const float* __restrict__ S, const float* __restrict__ Bi,
                  float* __restrict__ O)
{
    const int n = (int)blockIdx.x;
    const int m = (int)threadIdx.x;
    float s = 0.f;
    for (int k = 0; k < K; ++k)
        s += (float)(_Float16)X[(size_t)m * K + k] * (float)(_Float16)W[(size_t)n * K + k];
    O[(size_t)m * N + n] = (float)(_Float16)((float)(_Float16)(s * S[n]) + Bi[n]);
}

extern "C" void kernel_launch(void* const* d_in, const int* in_sizes, int n_in,
                              void* d_out, int out_size, void* d_ws, size_t ws_size,
                              hipStream_t stream) {
    const float* x  = (const float*)d_in[0];
    const float* w  = (const float*)d_in[1];
    const float* s  = (const float*)d_in[2];
    const float* bi = (const float*)d_in[3];
    float* o  = (float*)d_out;
    float* ws = (float*)d_ws;

    const size_t slice = (size_t)M * N * sizeof(float);   // 4 MB

    if (ws_size >= SPL * slice) {
        fp6lin_gemm<<<dim3(2 * 32 * SPL), dim3(512), 0, stream>>>(x, w, ws);
        fp6lin_finalize<SPL><<<dim3(M * N / 4 / 256), dim3(256), 0, stream>>>(ws, s, bi, o);
    } else {
        fp6lin_small<<<dim3(N), dim3(M), 0, stream>>>(x, w, s, bi, o);
    }
}